// Round 2
// baseline (2038.364 us; speedup 1.0000x reference)
//
#include <hip/hip_runtime.h>
#include <math.h>

// Problem constants: B=8, T=8, CIN=64, FN=64, H=W=32, HW=1024, GROUPS=8
// ws layout (floats):
//  ic     @ 0        (524288)
//  ih     @ 524288   (524288)
//  im     @ 1048576  (524288)
//  gates0 @ 1572864  (2097152)   [also reused as gates2 later in step]
//  gates1 @ 3670016  (2097152)   [also reused as zcat0/zcat1 later in step]
//  gnstat @ 5767168  (256)
//  qkv    @ 5767424  (1572864)   [B][192][1024]: Q 0-63, Kh 64-127, Vh 128-191
//  mkv    @ 7340288  (1048576)   [B][128][1024]: Km 0-63, Vm 64-127
//  stats  @ 8388864  (65536)     [B][att2][mh2][{M,D}][1024]
//  cat2   @ 8454400  (1048576)   [B][128][1024]: Zc rows 0-63, oh rows 64-127
// total 9502976 floats = 38 MB

#define DEV __device__ __forceinline__

DEV float sigm(float x) { return 1.0f / (1.0f + __expf(-x)); }

#define FMA16(A, av, bv) do { \
  A[0][0] = fmaf(av.x, bv.x, A[0][0]); A[0][1] = fmaf(av.x, bv.y, A[0][1]); \
  A[0][2] = fmaf(av.x, bv.z, A[0][2]); A[0][3] = fmaf(av.x, bv.w, A[0][3]); \
  A[1][0] = fmaf(av.y, bv.x, A[1][0]); A[1][1] = fmaf(av.y, bv.y, A[1][1]); \
  A[1][2] = fmaf(av.y, bv.z, A[1][2]); A[1][3] = fmaf(av.y, bv.w, A[1][3]); \
  A[2][0] = fmaf(av.z, bv.x, A[2][0]); A[2][1] = fmaf(av.z, bv.y, A[2][1]); \
  A[2][2] = fmaf(av.z, bv.z, A[2][2]); A[2][3] = fmaf(av.z, bv.w, A[2][3]); \
  A[3][0] = fmaf(av.w, bv.x, A[3][0]); A[3][1] = fmaf(av.w, bv.y, A[3][1]); \
  A[3][2] = fmaf(av.w, bv.z, A[3][2]); A[3][3] = fmaf(av.w, bv.w, A[3][3]); \
} while (0)

// ---------------------------------------------------------------------------
// Conv 3x3 SAME. Split-K: chalf 0 -> x_t channels (adds bias), chalf 1 -> ih.
// Block: 256 thr, 8 output channels, full 32x32 image, 4 px/thread.
// grid (32 octiles, 8 b, 2 chalf) = 512 blocks.
// ---------------------------------------------------------------------------
__global__ __launch_bounds__(256) void conv3_kernel(
    const float* __restrict__ x,    // [B][T][64][1024]
    const float* __restrict__ ihb,  // [B][64][1024]
    const float* __restrict__ w,    // [256][128][9]
    const float* __restrict__ bias, // [256]
    float* __restrict__ g0, float* __restrict__ g1, int t)
{
  int oc0   = blockIdx.x * 8;
  int b     = blockIdx.y;
  int chalf = blockIdx.z;
  __shared__ float wl[64 * 72];   // [c_local][tap][oc8]
  __shared__ float img[34 * 40];  // image (iy,ix) at [iy+1][4+ix]; border zero
  int tid = threadIdx.x;

  for (int f = tid; f < 4608; f += 256) {
    int oc = f / 576; int r = f - oc * 576;
    int cl = r / 9;   int tap = r - cl * 9;
    wl[cl * 72 + tap * 8 + oc] = w[(size_t)(oc0 + oc) * 1152 + chalf * 576 + r];
  }
  for (int f = tid; f < 34 * 40; f += 256) {
    int row = f / 40; int col = f - row * 40;
    if (row == 0 || row == 33 || col < 4 || col >= 36) img[f] = 0.0f;
  }

  int pix = tid * 4; int y = pix >> 5; int xc = pix & 31;
  const float* src0 = chalf ? (ihb + (size_t)b * 65536)
                            : (x + ((size_t)(b * 8 + t) * 64) * 1024);
  float acc[8][4] = {};

  for (int c = 0; c < 64; ++c) {
    __syncthreads();
    float4 v = *(const float4*)(src0 + (size_t)c * 1024 + pix);
    *(float4*)&img[(y + 1) * 40 + 4 + xc] = v;
    __syncthreads();
    const float* wc = &wl[c * 72];
#pragma unroll
    for (int dy = 0; dy < 3; ++dy) {
      const float* row = &img[(y + dy) * 40 + 4 + xc];
      float4 v4 = *(const float4*)row;
      float vl = row[-1], vr = row[4];
      float vals[6] = {vl, v4.x, v4.y, v4.z, v4.w, vr};
#pragma unroll
      for (int dx = 0; dx < 3; ++dx) {
        const float* wp = wc + (dy * 3 + dx) * 8;
        float4 w0 = *(const float4*)wp;
        float4 w1 = *(const float4*)(wp + 4);
#pragma unroll
        for (int p = 0; p < 4; ++p) {
          float xv = vals[dx + p];
          acc[0][p] = fmaf(xv, w0.x, acc[0][p]);
          acc[1][p] = fmaf(xv, w0.y, acc[1][p]);
          acc[2][p] = fmaf(xv, w0.z, acc[2][p]);
          acc[3][p] = fmaf(xv, w0.w, acc[3][p]);
          acc[4][p] = fmaf(xv, w1.x, acc[4][p]);
          acc[5][p] = fmaf(xv, w1.y, acc[5][p]);
          acc[6][p] = fmaf(xv, w1.z, acc[6][p]);
          acc[7][p] = fmaf(xv, w1.w, acc[7][p]);
        }
      }
    }
  }
  float* go = (chalf ? g1 : g0) + ((size_t)b * 256 + oc0) * 1024 + pix;
#pragma unroll
  for (int oc = 0; oc < 8; ++oc) {
    float bv = chalf ? 0.0f : bias[oc0 + oc];
    float4 o = make_float4(acc[oc][0] + bv, acc[oc][1] + bv,
                           acc[oc][2] + bv, acc[oc][3] + bv);
    *(float4*)(go + (size_t)oc * 1024) = o;
  }
}

// ---------------------------------------------------------------------------
// GroupNorm stats: per (b, group of 32 ch) over 32768 elements of g0+g1.
// grid (8 groups, 8 b), 256 thr.
// ---------------------------------------------------------------------------
__global__ __launch_bounds__(256) void gnstats_kernel(
    const float* __restrict__ g0, const float* __restrict__ g1,
    float* __restrict__ st)
{
  int grp = blockIdx.x; int b = blockIdx.y;
  const float* p0 = g0 + (size_t)b * 262144 + (size_t)grp * 32768;
  const float* p1 = g1 + (size_t)b * 262144 + (size_t)grp * 32768;
  float s = 0.0f, q = 0.0f;
  for (int i = threadIdx.x; i < 8192; i += 256) {
    float4 a = *(const float4*)(p0 + (size_t)i * 4);
    float4 c = *(const float4*)(p1 + (size_t)i * 4);
    float v0 = a.x + c.x, v1 = a.y + c.y, v2 = a.z + c.z, v3 = a.w + c.w;
    s += v0 + v1 + v2 + v3;
    q += v0 * v0 + v1 * v1 + v2 * v2 + v3 * v3;
  }
#pragma unroll
  for (int off = 32; off > 0; off >>= 1) {
    s += __shfl_down(s, off);
    q += __shfl_down(q, off);
  }
  __shared__ float ss[4], qq[4];
  int wid = threadIdx.x >> 6;
  if ((threadIdx.x & 63) == 0) { ss[wid] = s; qq[wid] = q; }
  __syncthreads();
  if (threadIdx.x == 0) {
    float S = ss[0] + ss[1] + ss[2] + ss[3];
    float Q = qq[0] + qq[1] + qq[2] + qq[3];
    float mu = S / 32768.0f;
    float var = Q / 32768.0f - mu * mu;
    st[(b * 8 + grp) * 2]     = mu;
    st[(b * 8 + grp) * 2 + 1] = rsqrtf(var + 1e-5f);
  }
}

// ---------------------------------------------------------------------------
// GN apply + LSTM gates. grid (64 ch, 8 b), 256 thr, 4 px/thread.
// Writes: ic (new oc), cat2 bottom half (oh), d_out ocT tail.
// ---------------------------------------------------------------------------
__global__ __launch_bounds__(256) void gnlstm_kernel(
    const float* __restrict__ g0, const float* __restrict__ g1,
    const float* __restrict__ st, const float* __restrict__ gn_g,
    const float* __restrict__ gn_b, float* __restrict__ ic,
    float* __restrict__ cat2, float* __restrict__ out)
{
  int c = blockIdx.x; int b = blockIdx.y;
  int px = threadIdx.x * 4;
  size_t base = (size_t)b * 262144 + (size_t)c * 1024 + px;

  float4 vi4 = *(const float4*)(g0 + base);
  float4 t4  = *(const float4*)(g1 + base);
  vi4.x += t4.x; vi4.y += t4.y; vi4.z += t4.z; vi4.w += t4.w;
  float4 vf4 = *(const float4*)(g0 + base + 65536);
  t4 = *(const float4*)(g1 + base + 65536);
  vf4.x += t4.x; vf4.y += t4.y; vf4.z += t4.z; vf4.w += t4.w;
  float4 vc4 = *(const float4*)(g0 + base + 131072);
  t4 = *(const float4*)(g1 + base + 131072);
  vc4.x += t4.x; vc4.y += t4.y; vc4.z += t4.z; vc4.w += t4.w;
  float4 vo4 = *(const float4*)(g0 + base + 196608);
  t4 = *(const float4*)(g1 + base + 196608);
  vo4.x += t4.x; vo4.y += t4.y; vo4.z += t4.z; vo4.w += t4.w;

  int ch0 = c, ch1 = 64 + c, ch2 = 128 + c, ch3 = 192 + c;
  float mu, is;
  mu = st[(b * 8 + (ch0 >> 5)) * 2]; is = st[(b * 8 + (ch0 >> 5)) * 2 + 1];
  float ga0 = gn_g[ch0] * is, bb0 = gn_b[ch0] - mu * ga0;
  mu = st[(b * 8 + (ch1 >> 5)) * 2]; is = st[(b * 8 + (ch1 >> 5)) * 2 + 1];
  float ga1 = gn_g[ch1] * is, bb1 = gn_b[ch1] - mu * ga1;
  mu = st[(b * 8 + (ch2 >> 5)) * 2]; is = st[(b * 8 + (ch2 >> 5)) * 2 + 1];
  float ga2 = gn_g[ch2] * is, bb2 = gn_b[ch2] - mu * ga2;
  mu = st[(b * 8 + (ch3 >> 5)) * 2]; is = st[(b * 8 + (ch3 >> 5)) * 2 + 1];
  float ga3 = gn_g[ch3] * is, bb3 = gn_b[ch3] - mu * ga3;

  size_t sb = (size_t)b * 65536 + (size_t)c * 1024 + px;
  float4 icv = *(const float4*)(ic + sb);
  float* vip = (float*)&vi4; float* vfp = (float*)&vf4;
  float* vcp = (float*)&vc4; float* vop = (float*)&vo4;
  float* icp = (float*)&icv;
  float4 ocv, ohv;
  float* ocp = (float*)&ocv; float* ohp = (float*)&ohv;
#pragma unroll
  for (int j = 0; j < 4; ++j) {
    float ing = sigm(vip[j] * ga0 + bb0);
    float fg  = sigm(vfp[j] * ga1 + bb1);
    float cg  = tanhf(vcp[j] * ga2 + bb2);
    float og  = sigm(vop[j] * ga3 + bb3);
    float oc  = icp[j] * fg + ing * cg;
    ocp[j] = oc;
    ohp[j] = og * tanhf(oc);
  }
  *(float4*)(ic + sb) = ocv;
  *(float4*)(out + 4718592 + sb) = ocv;  // ocT tail (final step persists)
  *(float4*)(cat2 + (size_t)b * 131072 + (size_t)(64 + c) * 1024 + px) = ohv;
}

// ---------------------------------------------------------------------------
// Generic GEMM: C[b][m][n] = sum_k W[m][k] * (X[b][k][n] (+X2)) + bias[m]
// grid (16 ntile, M/64 mtile, 8 b), 256 thr, 4x4 reg tile, K in {64,128}.
// ---------------------------------------------------------------------------
__global__ __launch_bounds__(256) void gemm_kernel(
    const float* __restrict__ W, const float* __restrict__ X,
    const float* __restrict__ X2, const float* __restrict__ bias,
    float* __restrict__ C, int K, int xbs, int cbs)
{
  int nt = blockIdx.x, mt = blockIdx.y, b = blockIdx.z;
  __shared__ float Xs[64 * 64];
  __shared__ float Wt[64 * 68];
  int tid = threadIdx.x;
  int mq = tid >> 4, nq = tid & 15;
  float acc[4][4] = {};
  const float* Xb  = X + (size_t)b * xbs + nt * 64;
  const float* X2b = X2 ? (X2 + (size_t)b * xbs + nt * 64) : nullptr;

  for (int k0 = 0; k0 < K; k0 += 64) {
    __syncthreads();
#pragma unroll
    for (int i = 0; i < 4; ++i) {
      int f = tid + i * 256;
      int kr = f >> 4; int nc = (f & 15) * 4;
      float4 v = *(const float4*)(Xb + (size_t)(k0 + kr) * 1024 + nc);
      if (X2b) {
        float4 v2 = *(const float4*)(X2b + (size_t)(k0 + kr) * 1024 + nc);
        v.x += v2.x; v.y += v2.y; v.z += v2.z; v.w += v2.w;
      }
      *(float4*)&Xs[kr * 64 + nc] = v;
      int mr = kr; int kc = nc;  // same decomposition for W tile
      float4 wv = *(const float4*)(W + (size_t)(mt * 64 + mr) * K + k0 + kc);
      Wt[(kc + 0) * 68 + mr] = wv.x;
      Wt[(kc + 1) * 68 + mr] = wv.y;
      Wt[(kc + 2) * 68 + mr] = wv.z;
      Wt[(kc + 3) * 68 + mr] = wv.w;
    }
    __syncthreads();
#pragma unroll 8
    for (int kk = 0; kk < 64; ++kk) {
      float4 wv = *(float4*)&Wt[kk * 68 + mq * 4];
      float4 xv = *(float4*)&Xs[kk * 64 + nq * 4];
      FMA16(acc, wv, xv);
    }
  }
  float* Cb = C + (size_t)b * cbs + (size_t)(mt * 64 + mq * 4) * 1024 + nt * 64 + nq * 4;
#pragma unroll
  for (int i = 0; i < 4; ++i) {
    float bv = bias ? bias[mt * 64 + mq * 4 + i] : 0.0f;
    float4 o = make_float4(acc[i][0] + bv, acc[i][1] + bv,
                           acc[i][2] + bv, acc[i][3] + bv);
    *(float4*)(Cb + (size_t)i * 1024) = o;
  }
}

// ---------------------------------------------------------------------------
// Attention pass 1: per-row (over m) max & sumexp of S = Q^T K.
// grid (16 ntile, 4 = att*2+mhalf, 8 b), 256 thr.
// stats layout: [b][att][mh][{M,D}][1024]
// ---------------------------------------------------------------------------
__global__ __launch_bounds__(256) void att_stats_kernel(
    const float* __restrict__ qkv, const float* __restrict__ mkv,
    float* __restrict__ stats)
{
  int nt = blockIdx.x;
  int att = blockIdx.y >> 1;
  int mh  = blockIdx.y & 1;
  int b = blockIdx.z;
  const float* Qb = qkv + (size_t)b * 196608 + nt * 64;
  const float* Kb = att ? (mkv + (size_t)b * 131072)
                        : (qkv + (size_t)b * 196608 + 65536);
  __shared__ float Qs[64 * 64];
  __shared__ float Ks[64 * 64];
  int tid = threadIdx.x; int nq = tid >> 4, mq = tid & 15;
#pragma unroll
  for (int i = 0; i < 4; ++i) {
    int f = tid + i * 256; int c = f >> 4; int n4 = (f & 15) * 4;
    *(float4*)&Qs[c * 64 + n4] = *(const float4*)(Qb + (size_t)c * 1024 + n4);
  }
  float M[4] = {-3.0e38f, -3.0e38f, -3.0e38f, -3.0e38f};
  float D[4] = {0.0f, 0.0f, 0.0f, 0.0f};

  for (int mt = mh * 8; mt < mh * 8 + 8; ++mt) {
    __syncthreads();
#pragma unroll
    for (int i = 0; i < 4; ++i) {
      int f = tid + i * 256; int c = f >> 4; int m4 = (f & 15) * 4;
      *(float4*)&Ks[c * 64 + m4] =
          *(const float4*)(Kb + (size_t)c * 1024 + mt * 64 + m4);
    }
    __syncthreads();
    float a[4][4] = {};
#pragma unroll 4
    for (int c = 0; c < 64; ++c) {
      float4 q = *(float4*)&Qs[c * 64 + nq * 4];
      float4 k = *(float4*)&Ks[c * 64 + mq * 4];
      FMA16(a, q, k);
    }
#pragma unroll
    for (int i = 0; i < 4; ++i) {
      float t0 = fmaxf(fmaxf(a[i][0], a[i][1]), fmaxf(a[i][2], a[i][3]));
      float nm = fmaxf(M[i], t0);
      float s = __expf(a[i][0] - nm) + __expf(a[i][1] - nm) +
                __expf(a[i][2] - nm) + __expf(a[i][3] - nm);
      D[i] = D[i] * __expf(M[i] - nm) + s;
      M[i] = nm;
    }
  }
#pragma unroll
  for (int off = 1; off < 16; off <<= 1) {
#pragma unroll
    for (int i = 0; i < 4; ++i) {
      float Mo = __shfl_xor(M[i], off);
      float Do = __shfl_xor(D[i], off);
      float nm = fmaxf(M[i], Mo);
      D[i] = D[i] * __expf(M[i] - nm) + Do * __expf(Mo - nm);
      M[i] = nm;
    }
  }
  if (mq == 0) {
    size_t sb = ((size_t)((b * 2 + att) * 2 + mh) * 2) * 1024 + nt * 64 + nq * 4;
#pragma unroll
    for (int i = 0; i < 4; ++i) {
      stats[sb + i] = M[i];
      stats[sb + 1024 + i] = D[i];
    }
  }
}

// ---------------------------------------------------------------------------
// Attention pass 2: Z[c][m] = sum_n V[c][n] * exp(S[n][m]-M[n]) / D[n].
// grid (16 mtile, 4 = att*2+nhalf, 8 b), 256 thr. Partial-Z per nhalf,
// summed later inside z1 gemm (X + X2).
// ---------------------------------------------------------------------------
__global__ __launch_bounds__(256) void att_z_kernel(
    const float* __restrict__ qkv, const float* __restrict__ mkv,
    const float* __restrict__ stats, float* __restrict__ z0,
    float* __restrict__ z1p)
{
  int mt = blockIdx.x;
  int att = blockIdx.y >> 1;
  int nh  = blockIdx.y & 1;
  int b = blockIdx.z;
  const float* Qb = qkv + (size_t)b * 196608;
  const float* Kb = att ? (mkv + (size_t)b * 131072)
                        : (qkv + (size_t)b * 196608 + 65536);
  const float* Vb = att ? (mkv + (size_t)b * 131072 + 65536)
                        : (qkv + (size_t)b * 196608 + 131072);
  __shared__ float Ks[64 * 64];
  __shared__ float Qs[64 * 64];
  __shared__ float Vs[64 * 68];
  __shared__ float Ps[64 * 64];
  int tid = threadIdx.x; int aq = tid >> 4, mq = tid & 15;
#pragma unroll
  for (int i = 0; i < 4; ++i) {
    int f = tid + i * 256; int c = f >> 4; int m4 = (f & 15) * 4;
    *(float4*)&Ks[c * 64 + m4] =
        *(const float4*)(Kb + (size_t)c * 1024 + mt * 64 + m4);
  }
  float z[4][4] = {};
  const float* stb = stats + (size_t)(b * 2 + att) * 4096;

  for (int ntb = nh * 8; ntb < nh * 8 + 8; ++ntb) {
    __syncthreads();
#pragma unroll
    for (int i = 0; i < 4; ++i) {
      int f = tid + i * 256; int c = f >> 4; int n4 = (f & 15) * 4;
      *(float4*)&Qs[c * 64 + n4] =
          *(const float4*)(Qb + (size_t)c * 1024 + ntb * 64 + n4);
      float4 vv = *(const float4*)(Vb + (size_t)c * 1024 + ntb * 64 + n4);
      Vs[(n4 + 0) * 68 + c] = vv.x;
      Vs[(n4 + 1) * 68 + c] = vv.y;
      Vs[(n4 + 2) * 68 + c] = vv.z;
      Vs[(n4 + 3) * 68 + c] = vv.w;
    }
    __syncthreads();
    float a[4][4] = {};
#pragma unroll 4
    for (int c = 0; c < 64; ++c) {
      float4 q = *(float4*)&Qs[c * 64 + aq * 4];
      float4 k = *(float4*)&Ks[c * 64 + mq * 4];
      FMA16(a, q, k);
    }
#pragma unroll
    for (int i = 0; i < 4; ++i) {
      int n = ntb * 64 + aq * 4 + i;
      float M0 = stb[n],        D0 = stb[1024 + n];
      float M1 = stb[2048 + n], D1 = stb[3072 + n];
      float Mm = fmaxf(M0, M1);
      float Dm = D0 * __expf(M0 - Mm) + D1 * __expf(M1 - Mm);
      float r = 1.0f / Dm;
      float4 p = make_float4(__expf(a[i][0] - Mm) * r, __expf(a[i][1] - Mm) * r,
                             __expf(a[i][2] - Mm) * r, __expf(a[i][3] - Mm) * r);
      *(float4*)&Ps[(aq * 4 + i) * 64 + mq * 4] = p;
    }
    __syncthreads();
#pragma unroll 4
    for (int n = 0; n < 64; ++n) {
      float4 vv = *(float4*)&Vs[n * 68 + aq * 4];
      float4 pv = *(float4*)&Ps[n * 64 + mq * 4];
      FMA16(z, vv, pv);
    }
  }
  float* zb = (nh ? z1p : z0) + (size_t)b * 131072 +
              (size_t)(att * 64 + aq * 4) * 1024 + mt * 64 + mq * 4;
#pragma unroll
  for (int i = 0; i < 4; ++i)
    *(float4*)(zb + (size_t)i * 1024) =
        make_float4(z[i][0], z[i][1], z[i][2], z[i][3]);
}

// ---------------------------------------------------------------------------
// SAM output gating. grid (64 ch, 8 b), 256 thr, 4 px/thread.
// Writes: im (om), ih (oh2), d_out[t], ohT & imT tails.
// ---------------------------------------------------------------------------
__global__ __launch_bounds__(256) void sam_kernel(
    const float* __restrict__ g2, float* __restrict__ im,
    float* __restrict__ ih, float* __restrict__ out, int t)
{
  int c = blockIdx.x; int b = blockIdx.y;
  int px = threadIdx.x * 4;
  size_t gb = (size_t)b * 196608 + (size_t)c * 1024 + px;
  float4 vo4 = *(const float4*)(g2 + gb);
  float4 vg4 = *(const float4*)(g2 + gb + 65536);
  float4 vi4 = *(const float4*)(g2 + gb + 131072);
  size_t sb = (size_t)b * 65536 + (size_t)c * 1024 + px;
  float4 vm4 = *(const float4*)(im + sb);
  float* vop = (float*)&vo4; float* vgp = (float*)&vg4;
  float* vip = (float*)&vi4; float* vmp = (float*)&vm4;
  float4 om4, oh4;
  float* omp = (float*)&om4; float* ohp = (float*)&oh4;
#pragma unroll
  for (int j = 0; j < 4; ++j) {
    float ig = sigm(vip[j]);
    float om = tanhf(vgp[j]) * ig + (1.0f - ig) * vmp[j];
    omp[j] = om;
    ohp[j] = sigm(vop[j]) * om;
  }
  *(float4*)(im + sb) = om4;
  *(float4*)(ih + sb) = oh4;
  *(float4*)(out + ((size_t)(b * 8 + t) * 64 + c) * 1024 + px) = oh4;
  *(float4*)(out + 4194304 + sb) = oh4;  // ohT tail
  *(float4*)(out + 5242880 + sb) = om4;  // imT tail
}

// ---------------------------------------------------------------------------
extern "C" void kernel_launch(void* const* d_in, const int* in_sizes, int n_in,
                              void* d_out, int out_size, void* d_ws,
                              size_t ws_size, hipStream_t stream)
{
  const float* x      = (const float*)d_in[0];
  const float* conv_w = (const float*)d_in[1];
  const float* conv_b = (const float*)d_in[2];
  const float* gn_g   = (const float*)d_in[3];
  const float* gn_b   = (const float*)d_in[4];
  const float* h_w    = (const float*)d_in[5];
  const float* h_b    = (const float*)d_in[6];
  const float* m_w    = (const float*)d_in[7];
  const float* m_b    = (const float*)d_in[8];
  const float* z1_w   = (const float*)d_in[9];
  const float* z1_b   = (const float*)d_in[10];
  const float* z2_w   = (const float*)d_in[11];
  const float* z2_b   = (const float*)d_in[12];
  float* out = (float*)d_out;
  float* ws  = (float*)d_ws;

  float* ic     = ws;
  float* ih     = ws + 524288;
  float* im     = ws + 1048576;
  float* gates0 = ws + 1572864;
  float* gates1 = ws + 3670016;
  float* gnst   = ws + 5767168;
  float* qkv    = ws + 5767424;
  float* mkv    = ws + 7340288;
  float* stats  = ws + 8388864;
  float* cat2   = ws + 8454400;
  float* zc0    = gates1;             // reuse after gnlstm
  float* zc1    = gates1 + 1048576;
  float* g2     = gates0;             // reuse after gnlstm

  // zero initial states ih, ic, im (contiguous)
  hipMemsetAsync(ic, 0, (size_t)3 * 524288 * sizeof(float), stream);

  for (int t = 0; t < 8; ++t) {
    conv3_kernel<<<dim3(32, 8, 2), 256, 0, stream>>>(x, ih, conv_w, conv_b,
                                                     gates0, gates1, t);
    gnstats_kernel<<<dim3(8, 8), 256, 0, stream>>>(gates0, gates1, gnst);
    gnlstm_kernel<<<dim3(64, 8), 256, 0, stream>>>(gates0, gates1, gnst, gn_g,
                                                   gn_b, ic, cat2, out);
    // projections: h_qkv = h_w @ oh (oh = cat2 rows 64..127); m_kv = m_w @ im
    gemm_kernel<<<dim3(16, 3, 8), 256, 0, stream>>>(
        h_w, cat2 + 65536, nullptr, h_b, qkv, 64, 131072, 196608);
    gemm_kernel<<<dim3(16, 2, 8), 256, 0, stream>>>(
        m_w, im, nullptr, m_b, mkv, 64, 65536, 131072);
    att_stats_kernel<<<dim3(16, 4, 8), 256, 0, stream>>>(qkv, mkv, stats);
    att_z_kernel<<<dim3(16, 4, 8), 256, 0, stream>>>(qkv, mkv, stats, zc0, zc1);
    // z1: Zc = z1_w @ (zc0 + zc1) -> cat2 top half
    gemm_kernel<<<dim3(16, 1, 8), 256, 0, stream>>>(
        z1_w, zc0, zc1, z1_b, cat2, 128, 131072, 131072);
    // z2: gates2 = z2_w @ cat2
    gemm_kernel<<<dim3(16, 3, 8), 256, 0, stream>>>(
        z2_w, cat2, nullptr, z2_b, g2, 128, 131072, 196608);
    sam_kernel<<<dim3(64, 8), 256, 0, stream>>>(g2, im, ih, out, t);
  }
}

// Round 5
// 1765.101 us; speedup vs baseline: 1.1548x; 1.1548x over previous
//
#include <hip/hip_runtime.h>
#include <math.h>

// Problem constants: B=8, T=8, CIN=64, FN=64, H=W=32, HW=1024, GROUPS=8
// ws layout (floats):
//  ic     @ 0        (524288)
//  ih     @ 524288   (524288)
//  im     @ 1048576  (524288)
//  gates  @ 1572864  (2097152)   [conv out; reused as g2 (z2 out) later]
//  gnstat @ 3670016  (256)
//  qkv    @ 3670272  (1572864)   [B][192][1024]: Q 0-63, Kh 64-127, Vh 128-191
//  mkv    @ 5243136  (1048576)   [B][128][1024]: Km 0-63, Vm 64-127
//  stats  @ 6291712  (65536)     [B][att2][mh2][{M,D}][1024]
//  cat2   @ 6357248  (1048576)   [B][128][1024]: Zc rows 0-63, oh rows 64-127
//  zc     @ 7405824  (1048576)   [B][128][1024]: Zh rows 0-63, Zm rows 64-127
//  wpack  @ 8454400  (184320 floats = 368640 bf16)  MFMA-packed conv weights
// total 8638720 floats = 34.6 MB  (round-2 verified 38 MB, so safe)

#define DEV __device__ __forceinline__

DEV float sigm(float x) { return 1.0f / (1.0f + __expf(-x)); }

DEV unsigned short f2bf(float f) {
  union { float f; unsigned u; } v; v.f = f;
  unsigned r = v.u + 0x7FFF + ((v.u >> 16) & 1);  // RNE
  return (unsigned short)(r >> 16);
}

typedef float f32x4 __attribute__((ext_vector_type(4)));
typedef short bf16x8 __attribute__((ext_vector_type(8)));

#define FMA16(A, av, bv) do { \
  A[0][0] = fmaf(av.x, bv.x, A[0][0]); A[0][1] = fmaf(av.x, bv.y, A[0][1]); \
  A[0][2] = fmaf(av.x, bv.z, A[0][2]); A[0][3] = fmaf(av.x, bv.w, A[0][3]); \
  A[1][0] = fmaf(av.y, bv.x, A[1][0]); A[1][1] = fmaf(av.y, bv.y, A[1][1]); \
  A[1][2] = fmaf(av.y, bv.z, A[1][2]); A[1][3] = fmaf(av.y, bv.w, A[1][3]); \
  A[2][0] = fmaf(av.z, bv.x, A[2][0]); A[2][1] = fmaf(av.z, bv.y, A[2][1]); \
  A[2][2] = fmaf(av.z, bv.z, A[2][2]); A[2][3] = fmaf(av.z, bv.w, A[2][3]); \
  A[3][0] = fmaf(av.w, bv.x, A[3][0]); A[3][1] = fmaf(av.w, bv.y, A[3][1]); \
  A[3][2] = fmaf(av.w, bv.z, A[3][2]); A[3][3] = fmaf(av.w, bv.w, A[3][3]); \
} while (0)

// ---------------------------------------------------------------------------
// Prepack conv weights to bf16 MFMA layout:
// wpack[oh 2][s 36][ocl 128][ci 40]   (ci 0..31 real, 32..39 = 0)
// slab s: chh = s/18, tap = (s%18)>>1, kc = s&1; input ch c = chh*64+kc*32+ci
// 368640 elements total; 1440 blocks x 256.
// ---------------------------------------------------------------------------
__global__ __launch_bounds__(256) void wprep_kernel(
    const float* __restrict__ w, unsigned short* __restrict__ wpack)
{
  int e = blockIdx.x * 256 + threadIdx.x;  // < 368640
  int ci = e % 40;   int r = e / 40;       // r < 9216
  int ocl = r % 128; r /= 128;             // r < 72
  int s = r % 36;    int oh = r / 36;      // oh < 2
  int chh = s / 18;
  int t2  = s % 18;
  int tap = t2 >> 1, kc = t2 & 1;
  unsigned short v = 0;
  if (ci < 32) {
    int oc = oh * 128 + ocl;
    int c  = chh * 64 + kc * 32 + ci;
    v = f2bf(w[(size_t)(oc * 128 + c) * 9 + tap]);
  }
  wpack[e] = v;
}

// ---------------------------------------------------------------------------
// Conv 3x3 SAME via bf16 MFMA (16x16x32), 9-shifted-taps, full K=1152.
// Block: 256 thr (4 waves), tile = 128 oc x 64 px (2 image rows).
// grid (16 ptile, 8 b, 2 oh) = 256 blocks.
// Image LDS: [4 rows][34 cols][136 ch] (128 real + 8 pad; halo zeroed).
// Weight LDS: double-buffered [128 oc][40 ci] slabs, 36 slabs streamed.
// ---------------------------------------------------------------------------
__global__ __launch_bounds__(256) void conv3_mfma_kernel(
    const float* __restrict__ x,    // [B][T][64][1024]
    const float* __restrict__ ihb,  // [B][64][1024]
    const unsigned short* __restrict__ wpack,
    const float* __restrict__ bias, // [256]
    float* __restrict__ gates, int t)
{
  int ptile = blockIdx.x;
  int b     = blockIdx.y;
  int oh    = blockIdx.z;

  __shared__ __align__(16) unsigned short img[4 * 34 * 136];   // 36992 B
  __shared__ __align__(16) unsigned short wbuf[2][128 * 40];   // 2 x 10240 B

  int tid  = threadIdx.x;
  int lane = tid & 63;
  int wv   = tid >> 6;
  int mrow = wv >> 1, ncol = wv & 1;
  int y0 = ptile * 2;

  // zero image LDS (halo cells + ch pad stay zero)
  for (int i = tid; i < 4 * 34 * 136 / 2; i += 256) ((unsigned*)img)[i] = 0u;
  __syncthreads();

  // fill real cells: 4 rows x 32 cols x 128 ch (x:0-63, ih:64-127)
  const float* xsrc = x + (size_t)(b * 8 + t) * 65536;
  const float* hsrc = ihb + (size_t)b * 65536;
#pragma unroll
  for (int i = 0; i < 16; ++i) {
    int u = tid + i * 256;          // 0..4095 quad-units
    int ch = u >> 5;                // 0..127
    int v5 = u & 31;
    int row = v5 >> 3;              // 0..3
    int col4 = (v5 & 7) * 4;        // 0..28
    int gy = y0 - 1 + row;
    if (gy >= 0 && gy < 32) {
      const float* src = (ch < 64) ? (xsrc + (size_t)ch * 1024)
                                   : (hsrc + (size_t)(ch - 64) * 1024);
      float4 f = *(const float4*)(src + gy * 32 + col4);
      int base = (row * 34 + col4 + 1) * 136 + ch;
      img[base]       = f2bf(f.x);
      img[base + 136] = f2bf(f.y);
      img[base + 272] = f2bf(f.z);
      img[base + 408] = f2bf(f.w);
    }
  }

  // weight slab stream: slab s is 2560 contiguous dwords
  const unsigned* wsl = (const unsigned*)wpack + (size_t)oh * 36 * 2560;
  unsigned* wb32 = (unsigned*)&wbuf[0][0];
#pragma unroll
  for (int k2 = 0; k2 < 10; ++k2)
    wb32[tid + k2 * 256] = wsl[tid + k2 * 256];
  __syncthreads();

  // per-lane fragment bases
  int aoff = (mrow * 64 + (lane & 15)) * 40 + (lane >> 4) * 8;  // elements
  int pb[2];
#pragma unroll
  for (int nf = 0; nf < 2; ++nf) {
    int pp = ncol * 32 + nf * 16 + (lane & 15);
    int rr = pp >> 5, cc = pp & 31;
    pb[nf] = (rr * 34 + cc) * 136 + (lane >> 4) * 8;
  }

  f32x4 acc[4][2] = {};
  unsigned wreg[10];

#pragma unroll
  for (int s = 0; s < 36; ++s) {
    int cur = s & 1;
    if (s < 35) {
      const unsigned* nsl = wsl + (s + 1) * 2560;
#pragma unroll
      for (int k2 = 0; k2 < 10; ++k2) wreg[k2] = nsl[tid + k2 * 256];
    }
    int chh = s / 18;
    int t2  = s % 18;
    int tap = t2 >> 1, kc = t2 & 1;
    int dy = tap / 3, dx = tap % 3;
    int toff = (dy * 34 + dx) * 136 + chh * 64 + kc * 32;  // compile-time

    bf16x8 a[4], bb[2];
#pragma unroll
    for (int mf = 0; mf < 4; ++mf)
      a[mf] = *(const bf16x8*)&wbuf[cur][aoff + mf * 640];
#pragma unroll
    for (int nf = 0; nf < 2; ++nf)
      bb[nf] = *(const bf16x8*)&img[pb[nf] + toff];
#pragma unroll
    for (int mf = 0; mf < 4; ++mf)
#pragma unroll
      for (int nf = 0; nf < 2; ++nf)
        acc[mf][nf] = __builtin_amdgcn_mfma_f32_16x16x32_bf16(
            a[mf], bb[nf], acc[mf][nf], 0, 0, 0);

    if (s < 35) {
      unsigned* dst = (unsigned*)&wbuf[0][0] + (1 - cur) * 2560;
#pragma unroll
      for (int k2 = 0; k2 < 10; ++k2) dst[tid + k2 * 256] = wreg[k2];
    }
    __syncthreads();
  }

  // epilogue: D col = lane&15 (pixel), row = (lane>>4)*4 + reg (oc)
  int orow_base = oh * 128 + mrow * 64 + (lane >> 4) * 4;
  int pcol = ptile * 64 + ncol * 32 + (lane & 15);
  float* gout = gates + (size_t)b * 262144;
#pragma unroll
  for (int mf = 0; mf < 4; ++mf)
#pragma unroll
    for (int nf = 0; nf < 2; ++nf)
#pragma unroll
      for (int r = 0; r < 4; ++r) {
        int oc_ = orow_base + mf * 16 + r;
        gout[(size_t)oc_ * 1024 + pcol + nf * 16] = acc[mf][nf][r] + bias[oc_];
      }
}

// ---------------------------------------------------------------------------
// GroupNorm stats: per (b, group of 32 ch) over 32768 elements of gates.
// ---------------------------------------------------------------------------
__global__ __launch_bounds__(256) void gnstats_kernel(
    const float* __restrict__ g, float* __restrict__ st)
{
  int grp = blockIdx.x; int b = blockIdx.y;
  const float* p0 = g + (size_t)b * 262144 + (size_t)grp * 32768;
  float s = 0.0f, q = 0.0f;
  for (int i = threadIdx.x; i < 8192; i += 256) {
    float4 a = *(const float4*)(p0 + (size_t)i * 4);
    s += a.x + a.y + a.z + a.w;
    q += a.x * a.x + a.y * a.y + a.z * a.z + a.w * a.w;
  }
#pragma unroll
  for (int off = 32; off > 0; off >>= 1) {
    s += __shfl_down(s, off);
    q += __shfl_down(q, off);
  }
  __shared__ float ss[4], qq[4];
  int wid = threadIdx.x >> 6;
  if ((threadIdx.x & 63) == 0) { ss[wid] = s; qq[wid] = q; }
  __syncthreads();
  if (threadIdx.x == 0) {
    float S = ss[0] + ss[1] + ss[2] + ss[3];
    float Q = qq[0] + qq[1] + qq[2] + qq[3];
    float mu = S / 32768.0f;
    float var = Q / 32768.0f - mu * mu;
    st[(b * 8 + grp) * 2]     = mu;
    st[(b * 8 + grp) * 2 + 1] = rsqrtf(var + 1e-5f);
  }
}

// ---------------------------------------------------------------------------
// GN apply + LSTM gates.
// ---------------------------------------------------------------------------
__global__ __launch_bounds__(256) void gnlstm_kernel(
    const float* __restrict__ g,
    const float* __restrict__ st, const float* __restrict__ gn_g,
    const float* __restrict__ gn_b, float* __restrict__ ic,
    float* __restrict__ cat2, float* __restrict__ out)
{
  int c = blockIdx.x; int b = blockIdx.y;
  int px = threadIdx.x * 4;
  size_t base = (size_t)b * 262144 + (size_t)c * 1024 + px;

  float4 vi4 = *(const float4*)(g + base);
  float4 vf4 = *(const float4*)(g + base + 65536);
  float4 vc4 = *(const float4*)(g + base + 131072);
  float4 vo4 = *(const float4*)(g + base + 196608);

  int ch0 = c, ch1 = 64 + c, ch2 = 128 + c, ch3 = 192 + c;
  float mu, is;
  mu = st[(b * 8 + (ch0 >> 5)) * 2]; is = st[(b * 8 + (ch0 >> 5)) * 2 + 1];
  float ga0 = gn_g[ch0] * is, bb0 = gn_b[ch0] - mu * ga0;
  mu = st[(b * 8 + (ch1 >> 5)) * 2]; is = st[(b * 8 + (ch1 >> 5)) * 2 + 1];
  float ga1 = gn_g[ch1] * is, bb1 = gn_b[ch1] - mu * ga1;
  mu = st[(b * 8 + (ch2 >> 5)) * 2]; is = st[(b * 8 + (ch2 >> 5)) * 2 + 1];
  float ga2 = gn_g[ch2] * is, bb2 = gn_b[ch2] - mu * ga2;
  mu = st[(b * 8 + (ch3 >> 5)) * 2]; is = st[(b * 8 + (ch3 >> 5)) * 2 + 1];
  float ga3 = gn_g[ch3] * is, bb3 = gn_b[ch3] - mu * ga3;

  size_t sb = (size_t)b * 65536 + (size_t)c * 1024 + px;
  float4 icv = *(const float4*)(ic + sb);
  float* vip = (float*)&vi4; float* vfp = (float*)&vf4;
  float* vcp = (float*)&vc4; float* vop = (float*)&vo4;
  float* icp = (float*)&icv;
  float4 ocv, ohv;
  float* ocp = (float*)&ocv; float* ohp = (float*)&ohv;
#pragma unroll
  for (int j = 0; j < 4; ++j) {
    float ing = sigm(vip[j] * ga0 + bb0);
    float fg  = sigm(vfp[j] * ga1 + bb1);
    float cg  = tanhf(vcp[j] * ga2 + bb2);
    float og  = sigm(vop[j] * ga3 + bb3);
    float oc  = icp[j] * fg + ing * cg;
    ocp[j] = oc;
    ohp[j] = og * tanhf(oc);
  }
  *(float4*)(ic + sb) = ocv;
  *(float4*)(out + 4718592 + sb) = ocv;  // ocT tail
  *(float4*)(cat2 + (size_t)b * 131072 + (size_t)(64 + c) * 1024 + px) = ohv;
}

// ---------------------------------------------------------------------------
// Generic GEMM: C[b][m][n] = sum_k W[m][k] * X[b][k][n] + bias[m]
// ---------------------------------------------------------------------------
__global__ __launch_bounds__(256) void gemm_kernel(
    const float* __restrict__ W, const float* __restrict__ X,
    const float* __restrict__ bias,
    float* __restrict__ C, int K, int xbs, int cbs)
{
  int nt = blockIdx.x, mt = blockIdx.y, b = blockIdx.z;
  __shared__ float Xs[64 * 64];
  __shared__ float Wt[64 * 68];
  int tid = threadIdx.x;
  int mq = tid >> 4, nq = tid & 15;
  float acc[4][4] = {};
  const float* Xb  = X + (size_t)b * xbs + nt * 64;

  for (int k0 = 0; k0 < K; k0 += 64) {
    __syncthreads();
#pragma unroll
    for (int i = 0; i < 4; ++i) {
      int f = tid + i * 256;
      int kr = f >> 4; int nc = (f & 15) * 4;
      float4 v = *(const float4*)(Xb + (size_t)(k0 + kr) * 1024 + nc);
      *(float4*)&Xs[kr * 64 + nc] = v;
      int mr = kr; int kc = nc;
      float4 wv = *(const float4*)(W + (size_t)(mt * 64 + mr) * K + k0 + kc);
      Wt[(kc + 0) * 68 + mr] = wv.x;
      Wt[(kc + 1) * 68 + mr] = wv.y;
      Wt[(kc + 2) * 68 + mr] = wv.z;
      Wt[(kc + 3) * 68 + mr] = wv.w;
    }
    __syncthreads();
#pragma unroll 8
    for (int kk = 0; kk < 64; ++kk) {
      float4 wv = *(float4*)&Wt[kk * 68 + mq * 4];
      float4 xv = *(float4*)&Xs[kk * 64 + nq * 4];
      FMA16(acc, wv, xv);
    }
  }
  float* Cb = C + (size_t)b * cbs + (size_t)(mt * 64 + mq * 4) * 1024 + nt * 64 + nq * 4;
#pragma unroll
  for (int i = 0; i < 4; ++i) {
    float bv = bias ? bias[mt * 64 + mq * 4 + i] : 0.0f;
    float4 o = make_float4(acc[i][0] + bv, acc[i][1] + bv,
                           acc[i][2] + bv, acc[i][3] + bv);
    *(float4*)(Cb + (size_t)i * 1024) = o;
  }
}

// ---------------------------------------------------------------------------
// Attention pass 1: per-row (over m) max & sumexp of S = Q^T K.
// grid (16 ntile, 4 = att*2+mhalf, 8 b); stats [b][att][mh][{M,D}][1024]
// ---------------------------------------------------------------------------
__global__ __launch_bounds__(256) void att_stats_kernel(
    const float* __restrict__ qkv, const float* __restrict__ mkv,
    float* __restrict__ stats)
{
  int nt = blockIdx.x;
  int att = blockIdx.y >> 1;
  int mh  = blockIdx.y & 1;
  int b = blockIdx.z;
  const float* Qb = qkv + (size_t)b * 196608 + nt * 64;
  const float* Kb = att ? (mkv + (size_t)b * 131072)
                        : (qkv + (size_t)b * 196608 + 65536);
  __shared__ float Qs[64 * 64];
  __shared__ float Ks[64 * 64];
  int tid = threadIdx.x; int nq = tid >> 4, mq = tid & 15;
#pragma unroll
  for (int i = 0; i < 4; ++i) {
    int f = tid + i * 256; int c = f >> 4; int n4 = (f & 15) * 4;
    *(float4*)&Qs[c * 64 + n4] = *(const float4*)(Qb + (size_t)c * 1024 + n4);
  }
  float M[4] = {-3.0e38f, -3.0e38f, -3.0e38f, -3.0e38f};
  float D[4] = {0.0f, 0.0f, 0.0f, 0.0f};

  for (int mt = mh * 8; mt < mh * 8 + 8; ++mt) {
    __syncthreads();
#pragma unroll
    for (int i = 0; i < 4; ++i) {
      int f = tid + i * 256; int c = f >> 4; int m4 = (f & 15) * 4;
      *(float4*)&Ks[c * 64 + m4] =
          *(const float4*)(Kb + (size_t)c * 1024 + mt * 64 + m4);
    }
    __syncthreads();
    float a[4][4] = {};
#pragma unroll 4
    for (int c = 0; c < 64; ++c) {
      float4 q = *(float4*)&Qs[c * 64 + nq * 4];
      float4 k = *(float4*)&Ks[c * 64 + mq * 4];
      FMA16(a, q, k);
    }
#pragma unroll
    for (int i = 0; i < 4; ++i) {
      float t0 = fmaxf(fmaxf(a[i][0], a[i][1]), fmaxf(a[i][2], a[i][3]));
      float nm = fmaxf(M[i], t0);
      float s = __expf(a[i][0] - nm) + __expf(a[i][1] - nm) +
                __expf(a[i][2] - nm) + __expf(a[i][3] - nm);
      D[i] = D[i] * __expf(M[i] - nm) + s;
      M[i] = nm;
    }
  }
#pragma unroll
  for (int off = 1; off < 16; off <<= 1) {
#pragma unroll
    for (int i = 0; i < 4; ++i) {
      float Mo = __shfl_xor(M[i], off);
      float Do = __shfl_xor(D[i], off);
      float nm = fmaxf(M[i], Mo);
      D[i] = D[i] * __expf(M[i] - nm) + Do * __expf(Mo - nm);
      M[i] = nm;
    }
  }
  if (mq == 0) {
    size_t sb = ((size_t)((b * 2 + att) * 2 + mh) * 2) * 1024 + nt * 64 + nq * 4;
#pragma unroll
    for (int i = 0; i < 4; ++i) {
      stats[sb + i] = M[i];
      stats[sb + 1024 + i] = D[i];
    }
  }
}

// ---------------------------------------------------------------------------
// Attention pass 2: Z[c][m] = sum_n V[c][n] * exp(S[n][m]-M[n]) / D[n].
// grid (16 mtile, 2 att, 8 b), 256 thr; all 16 n-tiles per block.
// ---------------------------------------------------------------------------
__global__ __launch_bounds__(256) void att_z_kernel(
    const float* __restrict__ qkv, const float* __restrict__ mkv,
    const float* __restrict__ stats, float* __restrict__ zc)
{
  int mt = blockIdx.x;
  int att = blockIdx.y;
  int b = blockIdx.z;
  const float* Qb = qkv + (size_t)b * 196608;
  const float* Kb = att ? (mkv + (size_t)b * 131072)
                        : (qkv + (size_t)b * 196608 + 65536);
  const float* Vb = att ? (mkv + (size_t)b * 131072 + 65536)
                        : (qkv + (size_t)b * 196608 + 131072);
  __shared__ float Ks[64 * 64];
  __shared__ float Qs[64 * 64];
  __shared__ float Vs[64 * 68];
  __shared__ float Ps[64 * 64];
  int tid = threadIdx.x; int aq = tid >> 4, mq = tid & 15;
#pragma unroll
  for (int i = 0; i < 4; ++i) {
    int f = tid + i * 256; int c = f >> 4; int m4 = (f & 15) * 4;
    *(float4*)&Ks[c * 64 + m4] =
        *(const float4*)(Kb + (size_t)c * 1024 + mt * 64 + m4);
  }
  float z[4][4] = {};
  const float* stb = stats + (size_t)(b * 2 + att) * 4096;

  for (int ntb = 0; ntb < 16; ++ntb) {
    __syncthreads();
#pragma unroll
    for (int i = 0; i < 4; ++i) {
      int f = tid + i * 256; int c = f >> 4; int n4 = (f & 15) * 4;
      *(float4*)&Qs[c * 64 + n4] =
          *(const float4*)(Qb + (size_t)c * 1024 + ntb * 64 + n4);
      float4 vv = *(const float4*)(Vb + (size_t)c * 1024 + ntb * 64 + n4);
      Vs[(n4 + 0) * 68 + c] = vv.x;
      Vs[(n4 + 1) * 68 + c] = vv.y;
      Vs[(n4 + 2) * 68 + c] = vv.z;
      Vs[(n4 + 3) * 68 + c] = vv.w;
    }
    __syncthreads();
    float a[4][4] = {};
#pragma unroll 4
    for (int c = 0; c < 64; ++c) {
      float4 q = *(float4*)&Qs[c * 64 + aq * 4];
      float4 k = *(float4*)&Ks[c * 64 + mq * 4];
      FMA16(a, q, k);
    }
#pragma unroll
    for (int i = 0; i < 4; ++i) {
      int n = ntb * 64 + aq * 4 + i;
      float M0 = stb[n],        D0 = stb[1024 + n];
      float M1 = stb[2048 + n], D1 = stb[3072 + n];
      float Mm = fmaxf(M0, M1);
      float Dm = D0 * __expf(M0 - Mm) + D1 * __expf(M1 - Mm);
      float r = 1.0f / Dm;
      float4 p = make_float4(__expf(a[i][0] - Mm) * r, __expf(a[i][1] - Mm) * r,
                             __expf(a[i][2] - Mm) * r, __expf(a[i][3] - Mm) * r);
      *(float4*)&Ps[(aq * 4 + i) * 64 + mq * 4] = p;
    }
    __syncthreads();
#pragma unroll 4
    for (int n = 0; n < 64; ++n) {
      float4 vv = *(float4*)&Vs[n * 68 + aq * 4];
      float4 pv = *(float4*)&Ps[n * 64 + mq * 4];
      FMA16(z, vv, pv);
    }
  }
  float* zb = zc + (size_t)b * 131072 +
              (size_t)(att * 64 + aq * 4) * 1024 + mt * 64 + mq * 4;
#pragma unroll
  for (int i = 0; i < 4; ++i)
    *(float4*)(zb + (size_t)i * 1024) =
        make_float4(z[i][0], z[i][1], z[i][2], z[i][3]);
}

// ---------------------------------------------------------------------------
// SAM output gating.
// ---------------------------------------------------------------------------
__global__ __launch_bounds__(256) void sam_kernel(
    const float* __restrict__ g2, float* __restrict__ im,
    float* __restrict__ ih, float* __restrict__ out, int t)
{
  int c = blockIdx.x; int b = blockIdx.y;
  int px = threadIdx.x * 4;
  size_t gb = (size_t)b * 196608 + (size_t)c * 1024 + px;
  float4 vo4 = *(const float4*)(g2 + gb);
  float4 vg4 = *(const float4*)(g2 + gb + 65536);
  float4 vi4 = *(const float4*)(g2 + gb + 131072);
  size_t sb = (size_t)b * 65536 + (size_t)c * 1024 + px;
  float4 vm4 = *(const float4*)(im + sb);
  float* vop = (float*)&vo4; float* vgp = (float*)&vg4;
  float* vip = (float*)&vi4; float* vmp = (float*)&vm4;
  float4 om4, oh4;
  float* omp = (float*)&om4; float* ohp = (float*)&oh4;
#pragma unroll
  for (int j = 0; j < 4; ++j) {
    float ig = sigm(vip[j]);
    float om = tanhf(vgp[j]) * ig + (1.0f - ig) * vmp[j];
    omp[j] = om;
    ohp[j] = sigm(vop[j]) * om;
  }
  *(float4*)(im + sb) = om4;
  *(float4*)(ih + sb) = oh4;
  *(float4*)(out + ((size_t)(b * 8 + t) * 64 + c) * 1024 + px) = oh4;
  *(float4*)(out + 4194304 + sb) = oh4;  // ohT tail
  *(float4*)(out + 5242880 + sb) = om4;  // imT tail
}

// ---------------------------------------------------------------------------
extern "C" void kernel_launch(void* const* d_in, const int* in_sizes, int n_in,
                              void* d_out, int out_size, void* d_ws,
                              size_t ws_size, hipStream_t stream)
{
  const float* x      = (const float*)d_in[0];
  const float* conv_w = (const float*)d_in[1];
  const float* conv_b = (const float*)d_in[2];
  const float* gn_g   = (const float*)d_in[3];
  const float* gn_b   = (const float*)d_in[4];
  const float* h_w    = (const float*)d_in[5];
  const float* h_b    = (const float*)d_in[6];
  const float* m_w    = (const float*)d_in[7];
  const float* m_b    = (const float*)d_in[8];
  const float* z1_w   = (const float*)d_in[9];
  const float* z1_b   = (const float*)d_in[10];
  const float* z2_w   = (const float*)d_in[11];
  const float* z2_b   = (const float*)d_in[12];
  float* out = (float*)d_out;
  float* ws  = (float*)d_ws;

  float* ic     = ws;
  float* ih     = ws + 524288;
  float* im     = ws + 1048576;
  float* gates  = ws + 1572864;
  float* gnst   = ws + 3670016;
  float* qkv    = ws + 3670272;
  float* mkv    = ws + 5243136;
  float* stats  = ws + 6291712;
  float* cat2   = ws + 6357248;
  float* zc     = ws + 7405824;
  unsigned short* wpack = (unsigned short*)(ws + 8454400);
  float* g2     = gates;              // reuse after gnlstm

  // zero initial states ih, ic, im (contiguous)
  hipMemsetAsync(ic, 0, (size_t)3 * 524288 * sizeof(float), stream);
  // prepack conv weights to MFMA layout (per-call; ws is re-poisoned)
  wprep_kernel<<<dim3(1440), 256, 0, stream>>>(conv_w, wpack);

  for (int t = 0; t < 8; ++t) {
    conv3_mfma_kernel<<<dim3(16, 8, 2), 256, 0, stream>>>(
        x, ih, wpack, conv_b, gates, t);
    gnstats_kernel<<<dim3(8, 8), 256, 0, stream>>>(gates, gnst);
    gnlstm_kernel<<<dim3(64, 8), 256, 0, stream>>>(gates, gnst, gn_g,
                                                   gn_b, ic, cat2, out);
    // projections: h_qkv = h_w @ oh (oh = cat2 rows 64..127); m_kv = m_w @ im
    gemm_kernel<<<dim3(16, 3, 8), 256, 0, stream>>>(
        h_w, cat2 + 65536, h_b, qkv, 64, 131072, 196608);
    gemm_kernel<<<dim3(16, 2, 8), 256, 0, stream>>>(
        m_w, im, m_b, mkv, 64, 65536, 131072);
    att_stats_kernel<<<dim3(16, 4, 8), 256, 0, stream>>>(qkv, mkv, stats);
    att_z_kernel<<<dim3(16, 2, 8), 256, 0, stream>>>(qkv, mkv, stats, zc);
    // z1: Zc = z1_w @ zc -> cat2 top half
    gemm_kernel<<<dim3(16, 1, 8), 256, 0, stream>>>(
        z1_w, zc, z1_b, cat2, 128, 131072, 131072);
    // z2: gates2 = z2_w @ cat2
    gemm_kernel<<<dim3(16, 3, 8), 256, 0, stream>>>(
        z2_w, cat2, z2_b, g2, 128, 131072, 196608);
    sam_kernel<<<dim3(64, 8), 256, 0, stream>>>(g2, im, ih, out, t);
  }
}

// Round 6
// 1132.011 us; speedup vs baseline: 1.8007x; 1.5593x over previous
//
#include <hip/hip_runtime.h>
#include <math.h>

// Problem constants: B=8, T=8, CIN=64, FN=64, H=W=32, HW=1024, GROUPS=8
// ws layout (floats):
//  ic     @ 0        (524288)
//  ih     @ 524288   (524288)
//  im     @ 1048576  (524288)
//  gates  @ 1572864  (2097152)   [conv out; reused as g2 (z2 out) later]
//  gnstat @ 3670016  (256)
//  qkv    @ 3670272  (1572864)   [B][192][1024]: Q 0-63, Kh 64-127, Vh 128-191
//  mkv    @ 5243136  (1048576)   [B][128][1024]: Km 0-63, Vm 64-127
//  stats  @ 6291712  (65536)     [b][att][{M,rD}][1024] (32768 used)
//  cat2   @ 6357248  (1048576)   [B][128][1024]: Zc rows 0-63, oh rows 64-127
//  zc     @ 7405824  (1048576)   [B][128][1024]: Zh rows 0-63, Zm rows 64-127
//  wpack  @ 8454400  (184320 floats = 368640 bf16)  MFMA-packed conv weights
// total 8638720 floats = 34.6 MB  (38 MB proven safe)

#define DEV __device__ __forceinline__

DEV float sigm(float x) { return 1.0f / (1.0f + __expf(-x)); }

DEV unsigned short f2bf(float f) {
  union { float f; unsigned u; } v; v.f = f;
  unsigned r = v.u + 0x7FFF + ((v.u >> 16) & 1);  // RNE
  return (unsigned short)(r >> 16);
}

DEV unsigned pk2(float a, float b) {
  return (unsigned)f2bf(a) | ((unsigned)f2bf(b) << 16);
}

typedef float f32x4 __attribute__((ext_vector_type(4)));
typedef short bf16x8 __attribute__((ext_vector_type(8)));

#define FMA16(A, av, bv) do { \
  A[0][0] = fmaf(av.x, bv.x, A[0][0]); A[0][1] = fmaf(av.x, bv.y, A[0][1]); \
  A[0][2] = fmaf(av.x, bv.z, A[0][2]); A[0][3] = fmaf(av.x, bv.w, A[0][3]); \
  A[1][0] = fmaf(av.y, bv.x, A[1][0]); A[1][1] = fmaf(av.y, bv.y, A[1][1]); \
  A[1][2] = fmaf(av.y, bv.z, A[1][2]); A[1][3] = fmaf(av.y, bv.w, A[1][3]); \
  A[2][0] = fmaf(av.z, bv.x, A[2][0]); A[2][1] = fmaf(av.z, bv.y, A[2][1]); \
  A[2][2] = fmaf(av.z, bv.z, A[2][2]); A[2][3] = fmaf(av.z, bv.w, A[2][3]); \
  A[3][0] = fmaf(av.w, bv.x, A[3][0]); A[3][1] = fmaf(av.w, bv.y, A[3][1]); \
  A[3][2] = fmaf(av.w, bv.z, A[3][2]); A[3][3] = fmaf(av.w, bv.w, A[3][3]); \
} while (0)

// ---------------------------------------------------------------------------
// Prepack conv weights to bf16 MFMA layout:
// wpack[oh 2][s 36][ocl 128][ci 40]   (ci 0..31 real, 32..39 = 0)
// ---------------------------------------------------------------------------
__global__ __launch_bounds__(256) void wprep_kernel(
    const float* __restrict__ w, unsigned short* __restrict__ wpack)
{
  int e = blockIdx.x * 256 + threadIdx.x;  // < 368640
  int ci = e % 40;   int r = e / 40;       // r < 9216
  int ocl = r % 128; r /= 128;             // r < 72
  int s = r % 36;    int oh = r / 36;      // oh < 2
  int chh = s / 18;
  int t2  = s % 18;
  int tap = t2 >> 1, kc = t2 & 1;
  unsigned short v = 0;
  if (ci < 32) {
    int oc = oh * 128 + ocl;
    int c  = chh * 64 + kc * 32 + ci;
    v = f2bf(w[(size_t)(oc * 128 + c) * 9 + tap]);
  }
  wpack[e] = v;
}

// ---------------------------------------------------------------------------
// Conv 3x3 SAME via bf16 MFMA (16x16x32), 9-shifted-taps, full K=1152.
// ---------------------------------------------------------------------------
__global__ __launch_bounds__(256) void conv3_mfma_kernel(
    const float* __restrict__ x,    // [B][T][64][1024]
    const float* __restrict__ ihb,  // [B][64][1024]
    const unsigned short* __restrict__ wpack,
    const float* __restrict__ bias, // [256]
    float* __restrict__ gates, int t)
{
  int ptile = blockIdx.x;
  int b     = blockIdx.y;
  int oh    = blockIdx.z;

  __shared__ __align__(16) unsigned short img[4 * 34 * 136];   // 36992 B
  __shared__ __align__(16) unsigned short wbuf[2][128 * 40];   // 2 x 10240 B

  int tid  = threadIdx.x;
  int lane = tid & 63;
  int wv   = tid >> 6;
  int mrow = wv >> 1, ncol = wv & 1;
  int y0 = ptile * 2;

  for (int i = tid; i < 4 * 34 * 136 / 2; i += 256) ((unsigned*)img)[i] = 0u;
  __syncthreads();

  const float* xsrc = x + (size_t)(b * 8 + t) * 65536;
  const float* hsrc = ihb + (size_t)b * 65536;
#pragma unroll
  for (int i = 0; i < 16; ++i) {
    int u = tid + i * 256;
    int ch = u >> 5;
    int v5 = u & 31;
    int row = v5 >> 3;
    int col4 = (v5 & 7) * 4;
    int gy = y0 - 1 + row;
    if (gy >= 0 && gy < 32) {
      const float* src = (ch < 64) ? (xsrc + (size_t)ch * 1024)
                                   : (hsrc + (size_t)(ch - 64) * 1024);
      float4 f = *(const float4*)(src + gy * 32 + col4);
      int base = (row * 34 + col4 + 1) * 136 + ch;
      img[base]       = f2bf(f.x);
      img[base + 136] = f2bf(f.y);
      img[base + 272] = f2bf(f.z);
      img[base + 408] = f2bf(f.w);
    }
  }

  const unsigned* wsl = (const unsigned*)wpack + (size_t)oh * 36 * 2560;
  unsigned* wb32 = (unsigned*)&wbuf[0][0];
#pragma unroll
  for (int k2 = 0; k2 < 10; ++k2)
    wb32[tid + k2 * 256] = wsl[tid + k2 * 256];
  __syncthreads();

  int aoff = (mrow * 64 + (lane & 15)) * 40 + (lane >> 4) * 8;
  int pb[2];
#pragma unroll
  for (int nf = 0; nf < 2; ++nf) {
    int pp = ncol * 32 + nf * 16 + (lane & 15);
    int rr = pp >> 5, cc = pp & 31;
    pb[nf] = (rr * 34 + cc) * 136 + (lane >> 4) * 8;
  }

  f32x4 acc[4][2] = {};
  unsigned wreg[10];

#pragma unroll
  for (int s = 0; s < 36; ++s) {
    int cur = s & 1;
    if (s < 35) {
      const unsigned* nsl = wsl + (s + 1) * 2560;
#pragma unroll
      for (int k2 = 0; k2 < 10; ++k2) wreg[k2] = nsl[tid + k2 * 256];
    }
    int chh = s / 18;
    int t2  = s % 18;
    int tap = t2 >> 1, kc = t2 & 1;
    int dy = tap / 3, dx = tap % 3;
    int toff = (dy * 34 + dx) * 136 + chh * 64 + kc * 32;

    bf16x8 a[4], bb[2];
#pragma unroll
    for (int mf = 0; mf < 4; ++mf)
      a[mf] = *(const bf16x8*)&wbuf[cur][aoff + mf * 640];
#pragma unroll
    for (int nf = 0; nf < 2; ++nf)
      bb[nf] = *(const bf16x8*)&img[pb[nf] + toff];
#pragma unroll
    for (int mf = 0; mf < 4; ++mf)
#pragma unroll
      for (int nf = 0; nf < 2; ++nf)
        acc[mf][nf] = __builtin_amdgcn_mfma_f32_16x16x32_bf16(
            a[mf], bb[nf], acc[mf][nf], 0, 0, 0);

    if (s < 35) {
      unsigned* dst = (unsigned*)&wbuf[0][0] + (1 - cur) * 2560;
#pragma unroll
      for (int k2 = 0; k2 < 10; ++k2) dst[tid + k2 * 256] = wreg[k2];
    }
    __syncthreads();
  }

  int orow_base = oh * 128 + mrow * 64 + (lane >> 4) * 4;
  int pcol = ptile * 64 + ncol * 32 + (lane & 15);
  float* gout = gates + (size_t)b * 262144;
#pragma unroll
  for (int mf = 0; mf < 4; ++mf)
#pragma unroll
    for (int nf = 0; nf < 2; ++nf)
#pragma unroll
      for (int r = 0; r < 4; ++r) {
        int oc_ = orow_base + mf * 16 + r;
        gout[(size_t)oc_ * 1024 + pcol + nf * 16] = acc[mf][nf][r] + bias[oc_];
      }
}

// ---------------------------------------------------------------------------
// GroupNorm stats
// ---------------------------------------------------------------------------
__global__ __launch_bounds__(256) void gnstats_kernel(
    const float* __restrict__ g, float* __restrict__ st)
{
  int grp = blockIdx.x; int b = blockIdx.y;
  const float* p0 = g + (size_t)b * 262144 + (size_t)grp * 32768;
  float s = 0.0f, q = 0.0f;
  for (int i = threadIdx.x; i < 8192; i += 256) {
    float4 a = *(const float4*)(p0 + (size_t)i * 4);
    s += a.x + a.y + a.z + a.w;
    q += a.x * a.x + a.y * a.y + a.z * a.z + a.w * a.w;
  }
#pragma unroll
  for (int off = 32; off > 0; off >>= 1) {
    s += __shfl_down(s, off);
    q += __shfl_down(q, off);
  }
  __shared__ float ss[4], qq[4];
  int wid = threadIdx.x >> 6;
  if ((threadIdx.x & 63) == 0) { ss[wid] = s; qq[wid] = q; }
  __syncthreads();
  if (threadIdx.x == 0) {
    float S = ss[0] + ss[1] + ss[2] + ss[3];
    float Q = qq[0] + qq[1] + qq[2] + qq[3];
    float mu = S / 32768.0f;
    float var = Q / 32768.0f - mu * mu;
    st[(b * 8 + grp) * 2]     = mu;
    st[(b * 8 + grp) * 2 + 1] = rsqrtf(var + 1e-5f);
  }
}

// ---------------------------------------------------------------------------
// GN apply + LSTM gates.
// ---------------------------------------------------------------------------
__global__ __launch_bounds__(256) void gnlstm_kernel(
    const float* __restrict__ g,
    const float* __restrict__ st, const float* __restrict__ gn_g,
    const float* __restrict__ gn_b, float* __restrict__ ic,
    float* __restrict__ cat2, float* __restrict__ out)
{
  int c = blockIdx.x; int b = blockIdx.y;
  int px = threadIdx.x * 4;
  size_t base = (size_t)b * 262144 + (size_t)c * 1024 + px;

  float4 vi4 = *(const float4*)(g + base);
  float4 vf4 = *(const float4*)(g + base + 65536);
  float4 vc4 = *(const float4*)(g + base + 131072);
  float4 vo4 = *(const float4*)(g + base + 196608);

  int ch0 = c, ch1 = 64 + c, ch2 = 128 + c, ch3 = 192 + c;
  float mu, is;
  mu = st[(b * 8 + (ch0 >> 5)) * 2]; is = st[(b * 8 + (ch0 >> 5)) * 2 + 1];
  float ga0 = gn_g[ch0] * is, bb0 = gn_b[ch0] - mu * ga0;
  mu = st[(b * 8 + (ch1 >> 5)) * 2]; is = st[(b * 8 + (ch1 >> 5)) * 2 + 1];
  float ga1 = gn_g[ch1] * is, bb1 = gn_b[ch1] - mu * ga1;
  mu = st[(b * 8 + (ch2 >> 5)) * 2]; is = st[(b * 8 + (ch2 >> 5)) * 2 + 1];
  float ga2 = gn_g[ch2] * is, bb2 = gn_b[ch2] - mu * ga2;
  mu = st[(b * 8 + (ch3 >> 5)) * 2]; is = st[(b * 8 + (ch3 >> 5)) * 2 + 1];
  float ga3 = gn_g[ch3] * is, bb3 = gn_b[ch3] - mu * ga3;

  size_t sb = (size_t)b * 65536 + (size_t)c * 1024 + px;
  float4 icv = *(const float4*)(ic + sb);
  float* vip = (float*)&vi4; float* vfp = (float*)&vf4;
  float* vcp = (float*)&vc4; float* vop = (float*)&vo4;
  float* icp = (float*)&icv;
  float4 ocv, ohv;
  float* ocp = (float*)&ocv; float* ohp = (float*)&ohv;
#pragma unroll
  for (int j = 0; j < 4; ++j) {
    float ing = sigm(vip[j] * ga0 + bb0);
    float fg  = sigm(vfp[j] * ga1 + bb1);
    float cg  = tanhf(vcp[j] * ga2 + bb2);
    float og  = sigm(vop[j] * ga3 + bb3);
    float oc  = icp[j] * fg + ing * cg;
    ocp[j] = oc;
    ohp[j] = og * tanhf(oc);
  }
  *(float4*)(ic + sb) = ocv;
  *(float4*)(out + 4718592 + sb) = ocv;  // ocT tail
  *(float4*)(cat2 + (size_t)b * 131072 + (size_t)(64 + c) * 1024 + px) = ohv;
}

// ---------------------------------------------------------------------------
// Generic GEMM: C[b][m][n] = sum_k W[m][k] * X[b][k][n] + bias[m]
// ---------------------------------------------------------------------------
__global__ __launch_bounds__(256) void gemm_kernel(
    const float* __restrict__ W, const float* __restrict__ X,
    const float* __restrict__ bias,
    float* __restrict__ C, int K, int xbs, int cbs)
{
  int nt = blockIdx.x, mt = blockIdx.y, b = blockIdx.z;
  __shared__ float Xs[64 * 64];
  __shared__ float Wt[64 * 68];
  int tid = threadIdx.x;
  int mq = tid >> 4, nq = tid & 15;
  float acc[4][4] = {};
  const float* Xb  = X + (size_t)b * xbs + nt * 64;

  for (int k0 = 0; k0 < K; k0 += 64) {
    __syncthreads();
#pragma unroll
    for (int i = 0; i < 4; ++i) {
      int f = tid + i * 256;
      int kr = f >> 4; int nc = (f & 15) * 4;
      float4 v = *(const float4*)(Xb + (size_t)(k0 + kr) * 1024 + nc);
      *(float4*)&Xs[kr * 64 + nc] = v;
      int mr = kr; int kc = nc;
      float4 wv = *(const float4*)(W + (size_t)(mt * 64 + mr) * K + k0 + kc);
      Wt[(kc + 0) * 68 + mr] = wv.x;
      Wt[(kc + 1) * 68 + mr] = wv.y;
      Wt[(kc + 2) * 68 + mr] = wv.z;
      Wt[(kc + 3) * 68 + mr] = wv.w;
    }
    __syncthreads();
#pragma unroll 8
    for (int kk = 0; kk < 64; ++kk) {
      float4 wv = *(float4*)&Wt[kk * 68 + mq * 4];
      float4 xv = *(float4*)&Xs[kk * 64 + nq * 4];
      FMA16(acc, wv, xv);
    }
  }
  float* Cb = C + (size_t)b * cbs + (size_t)(mt * 64 + mq * 4) * 1024 + nt * 64 + nq * 4;
#pragma unroll
  for (int i = 0; i < 4; ++i) {
    float bv = bias ? bias[mt * 64 + mq * 4 + i] : 0.0f;
    float4 o = make_float4(acc[i][0] + bv, acc[i][1] + bv,
                           acc[i][2] + bv, acc[i][3] + bv);
    *(float4*)(Cb + (size_t)i * 1024) = o;
  }
}

// ---------------------------------------------------------------------------
// Attention pass 1 (MFMA): per-row-n max & sumexp of S = Q^T K over all m.
// grid (16 nt, 2 att, 8 b), 256 thr (4 waves, wave = 16-row n-stripe).
// stats out: [b][att][{M, 1/D}][1024]
// ---------------------------------------------------------------------------
__global__ __launch_bounds__(256) void att_stats_kernel(
    const float* __restrict__ qkv, const float* __restrict__ mkv,
    float* __restrict__ stats)
{
  int nt = blockIdx.x, att = blockIdx.y, b = blockIdx.z;
  const float* Qb = qkv + (size_t)b * 196608;
  const float* Kb = att ? (mkv + (size_t)b * 131072)
                        : (qkv + (size_t)b * 196608 + 65536);
  __shared__ __align__(16) unsigned short Qs[64 * 72];
  __shared__ __align__(16) unsigned short Ks[64 * 72];
  int tid = threadIdx.x, lane = tid & 63, w = tid >> 6;
  int n0 = nt * 64;

  // stage Q^T tile: Qs[nl][c] (paired-c u32 stores)
#pragma unroll
  for (int i = 0; i < 8; ++i) {
    int u = tid + i * 256;
    int c2 = u >> 6, nl = u & 63;
    float f0 = Qb[(size_t)(2 * c2) * 1024 + n0 + nl];
    float f1 = Qb[(size_t)(2 * c2 + 1) * 1024 + n0 + nl];
    ((unsigned*)Qs)[nl * 36 + c2] = pk2(f0, f1);
  }
  __syncthreads();
  // persistent A-frags (rows = n-stripe of this wave)
  bf16x8 qa0 = *(const bf16x8*)&Qs[(w * 16 + (lane & 15)) * 72 + (lane >> 4) * 8];
  bf16x8 qa1 = *(const bf16x8*)&Qs[(w * 16 + (lane & 15)) * 72 + 32 + (lane >> 4) * 8];

  float M[4] = {-3.0e38f, -3.0e38f, -3.0e38f, -3.0e38f};
  float Dsum[4] = {0.f, 0.f, 0.f, 0.f};

  for (int mt = 0; mt < 16; ++mt) {
    __syncthreads();
    // stage K^T tile: Ks[ml][c]
#pragma unroll
    for (int i = 0; i < 8; ++i) {
      int u = tid + i * 256;
      int c2 = u >> 6, ml = u & 63;
      float f0 = Kb[(size_t)(2 * c2) * 1024 + mt * 64 + ml];
      float f1 = Kb[(size_t)(2 * c2 + 1) * 1024 + mt * 64 + ml];
      ((unsigned*)Ks)[ml * 36 + c2] = pk2(f0, f1);
    }
    __syncthreads();
    f32x4 s[4];
#pragma unroll
    for (int mf = 0; mf < 4; ++mf) {
      bf16x8 b0 = *(const bf16x8*)&Ks[(mf * 16 + (lane & 15)) * 72 + (lane >> 4) * 8];
      bf16x8 b1 = *(const bf16x8*)&Ks[(mf * 16 + (lane & 15)) * 72 + 32 + (lane >> 4) * 8];
      f32x4 tacc = {};
      tacc = __builtin_amdgcn_mfma_f32_16x16x32_bf16(qa0, b0, tacc, 0, 0, 0);
      tacc = __builtin_amdgcn_mfma_f32_16x16x32_bf16(qa1, b1, tacc, 0, 0, 0);
      s[mf] = tacc;
    }
#pragma unroll
    for (int r = 0; r < 4; ++r) {
      float v0 = s[0][r], v1 = s[1][r], v2 = s[2][r], v3 = s[3][r];
      float mx = fmaxf(fmaxf(v0, v1), fmaxf(v2, v3));
      float nm = fmaxf(M[r], mx);
      Dsum[r] = Dsum[r] * __expf(M[r] - nm) +
                __expf(v0 - nm) + __expf(v1 - nm) +
                __expf(v2 - nm) + __expf(v3 - nm);
      M[r] = nm;
    }
  }
  // reduce across the 16 lanes sharing the same n-rows (lane&15 varies)
#pragma unroll
  for (int off = 1; off < 16; off <<= 1) {
#pragma unroll
    for (int r = 0; r < 4; ++r) {
      float Mo = __shfl_xor(M[r], off);
      float Do = __shfl_xor(Dsum[r], off);
      float nm = fmaxf(M[r], Mo);
      Dsum[r] = Dsum[r] * __expf(M[r] - nm) + Do * __expf(Mo - nm);
      M[r] = nm;
    }
  }
  if ((lane & 15) == 0) {
    float* stb = stats + (size_t)(b * 2 + att) * 2048;
#pragma unroll
    for (int r = 0; r < 4; ++r) {
      int n = n0 + w * 16 + (lane >> 4) * 4 + r;
      stb[n] = M[r];
      stb[1024 + n] = 1.0f / Dsum[r];
    }
  }
}

// ---------------------------------------------------------------------------
// Attention pass 2 (MFMA): Z[c][m] = sum_n (V[c][n]*rD[n]) * exp(S[n][m]-M[n])
// grid (16 mt, 2 att, 8 b), 256 thr. K^T tile resident; per ntb stage
// Q^T + Vd, S-MFMA, P=exp to LDS (P^T layout), PV-MFMA accumulate.
// ---------------------------------------------------------------------------
__global__ __launch_bounds__(256) void att_z_kernel(
    const float* __restrict__ qkv, const float* __restrict__ mkv,
    const float* __restrict__ stats, float* __restrict__ zc)
{
  int mt = blockIdx.x, att = blockIdx.y, b = blockIdx.z;
  const float* Qb = qkv + (size_t)b * 196608;
  const float* Kb = att ? (mkv + (size_t)b * 131072)
                        : (qkv + (size_t)b * 196608 + 65536);
  const float* Vb = att ? (mkv + (size_t)b * 131072 + 65536)
                        : (qkv + (size_t)b * 196608 + 131072);
  const float* stM = stats + (size_t)(b * 2 + att) * 2048;
  const float* stR = stM + 1024;

  __shared__ __align__(16) unsigned short Ks[64 * 72];
  __shared__ __align__(16) unsigned short Qs[64 * 72];
  __shared__ __align__(16) unsigned short Vs[64 * 72];
  __shared__ __align__(16) unsigned short Ps[64 * 72];
  __shared__ float Mn[64];

  int tid = threadIdx.x, lane = tid & 63, w = tid >> 6;
  int m0 = mt * 64;

  // stage K^T tile once: Ks[ml][c]
#pragma unroll
  for (int i = 0; i < 8; ++i) {
    int u = tid + i * 256;
    int c2 = u >> 6, ml = u & 63;
    float f0 = Kb[(size_t)(2 * c2) * 1024 + m0 + ml];
    float f1 = Kb[(size_t)(2 * c2 + 1) * 1024 + m0 + ml];
    ((unsigned*)Ks)[ml * 36 + c2] = pk2(f0, f1);
  }
  __syncthreads();
  // persistent K B-frags (cols = m)
  bf16x8 bk[4][2];
#pragma unroll
  for (int mf = 0; mf < 4; ++mf) {
    bk[mf][0] = *(const bf16x8*)&Ks[(mf * 16 + (lane & 15)) * 72 + (lane >> 4) * 8];
    bk[mf][1] = *(const bf16x8*)&Ks[(mf * 16 + (lane & 15)) * 72 + 32 + (lane >> 4) * 8];
  }

  f32x4 zacc[4] = {};

  for (int ntb = 0; ntb < 16; ++ntb) {
    int n0 = ntb * 64;
    __syncthreads();  // previous iteration's reads complete
    // stage Q^T: Qs[nl][c]
#pragma unroll
    for (int i = 0; i < 8; ++i) {
      int u = tid + i * 256;
      int c2 = u >> 6, nl = u & 63;
      float f0 = Qb[(size_t)(2 * c2) * 1024 + n0 + nl];
      float f1 = Qb[(size_t)(2 * c2 + 1) * 1024 + n0 + nl];
      ((unsigned*)Qs)[nl * 36 + c2] = pk2(f0, f1);
    }
    // stage Vd[c][n] = V[c][n]*rD[n]  (natural layout, vectorized)
#pragma unroll
    for (int i = 0; i < 4; ++i) {
      int u = tid + i * 256;
      int c = u >> 4, n4 = (u & 15) * 4;
      float4 v = *(const float4*)(Vb + (size_t)c * 1024 + n0 + n4);
      float4 rv = *(const float4*)(stR + n0 + n4);
      unsigned* dst = (unsigned*)&Vs[c * 72 + n4];
      dst[0] = pk2(v.x * rv.x, v.y * rv.y);
      dst[1] = pk2(v.z * rv.z, v.w * rv.w);
    }
    if (tid < 64) Mn[tid] = stM[n0 + tid];
    __syncthreads();

    // S = Q^T K (rows = n-stripe w, cols = m 0..63), P = exp(S - M[n]) -> Ps^T
    bf16x8 qa0 = *(const bf16x8*)&Qs[(w * 16 + (lane & 15)) * 72 + (lane >> 4) * 8];
    bf16x8 qa1 = *(const bf16x8*)&Qs[(w * 16 + (lane & 15)) * 72 + 32 + (lane >> 4) * 8];
    float mr[4];
#pragma unroll
    for (int r = 0; r < 4; ++r) mr[r] = Mn[w * 16 + (lane >> 4) * 4 + r];
#pragma unroll
    for (int mf = 0; mf < 4; ++mf) {
      f32x4 tacc = {};
      tacc = __builtin_amdgcn_mfma_f32_16x16x32_bf16(qa0, bk[mf][0], tacc, 0, 0, 0);
      tacc = __builtin_amdgcn_mfma_f32_16x16x32_bf16(qa1, bk[mf][1], tacc, 0, 0, 0);
      unsigned* dst = (unsigned*)&Ps[(mf * 16 + (lane & 15)) * 72 +
                                     w * 16 + (lane >> 4) * 4];
      dst[0] = pk2(__expf(tacc[0] - mr[0]), __expf(tacc[1] - mr[1]));
      dst[1] = pk2(__expf(tacc[2] - mr[2]), __expf(tacc[3] - mr[3]));
    }
    __syncthreads();

    // Z += Vd (rows c-stripe w) x P (k = n)
    bf16x8 va0 = *(const bf16x8*)&Vs[(w * 16 + (lane & 15)) * 72 + (lane >> 4) * 8];
    bf16x8 va1 = *(const bf16x8*)&Vs[(w * 16 + (lane & 15)) * 72 + 32 + (lane >> 4) * 8];
#pragma unroll
    for (int mf = 0; mf < 4; ++mf) {
      bf16x8 p0 = *(const bf16x8*)&Ps[(mf * 16 + (lane & 15)) * 72 + (lane >> 4) * 8];
      bf16x8 p1 = *(const bf16x8*)&Ps[(mf * 16 + (lane & 15)) * 72 + 32 + (lane >> 4) * 8];
      zacc[mf] = __builtin_amdgcn_mfma_f32_16x16x32_bf16(va0, p0, zacc[mf], 0, 0, 0);
      zacc[mf] = __builtin_amdgcn_mfma_f32_16x16x32_bf16(va1, p1, zacc[mf], 0, 0, 0);
    }
  }

  // write Z: row c = w*16+(lane>>4)*4+r, col m = m0 + mf*16 + (lane&15)
  float* zb = zc + (size_t)b * 131072 + (size_t)att * 65536;
#pragma unroll
  for (int mf = 0; mf < 4; ++mf)
#pragma unroll
    for (int r = 0; r < 4; ++r) {
      int c = w * 16 + (lane >> 4) * 4 + r;
      zb[(size_t)c * 1024 + m0 + mf * 16 + (lane & 15)] = zacc[mf][r];
    }
}

// ---------------------------------------------------------------------------
// SAM output gating.
// ---------------------------------------------------------------------------
__global__ __launch_bounds__(256) void sam_kernel(
    const float* __restrict__ g2, float* __restrict__ im,
    float* __restrict__ ih, float* __restrict__ out, int t)
{
  int c = blockIdx.x; int b = blockIdx.y;
  int px = threadIdx.x * 4;
  size_t gb = (size_t)b * 196608 + (size_t)c * 1024 + px;
  float4 vo4 = *(const float4*)(g2 + gb);
  float4 vg4 = *(const float4*)(g2 + gb + 65536);
  float4 vi4 = *(const float4*)(g2 + gb + 131072);
  size_t sb = (size_t)b * 65536 + (size_t)c * 1024 + px;
  float4 vm4 = *(const float4*)(im + sb);
  float* vop = (float*)&vo4; float* vgp = (float*)&vg4;
  float* vip = (float*)&vi4; float* vmp = (float*)&vm4;
  float4 om4, oh4;
  float* omp = (float*)&om4; float* ohp = (float*)&oh4;
#pragma unroll
  for (int j = 0; j < 4; ++j) {
    float ig = sigm(vip[j]);
    float om = tanhf(vgp[j]) * ig + (1.0f - ig) * vmp[j];
    omp[j] = om;
    ohp[j] = sigm(vop[j]) * om;
  }
  *(float4*)(im + sb) = om4;
  *(float4*)(ih + sb) = oh4;
  *(float4*)(out + ((size_t)(b * 8 + t) * 64 + c) * 1024 + px) = oh4;
  *(float4*)(out + 4194304 + sb) = oh4;  // ohT tail
  *(float4*)(out + 5242880 + sb) = om4;  // imT tail
}

// ---------------------------------------------------------------------------
extern "C" void kernel_launch(void* const* d_in, const int* in_sizes, int n_in,
                              void* d_out, int out_size, void* d_ws,
                              size_t ws_size, hipStream_t stream)
{
  const float* x      = (const float*)d_in[0];
  const float* conv_w = (const float*)d_in[1];
  const float* conv_b = (const float*)d_in[2];
  const float* gn_g   = (const float*)d_in[3];
  const float* gn_b   = (const float*)d_in[4];
  const float* h_w    = (const float*)d_in[5];
  const float* h_b    = (const float*)d_in[6];
  const float* m_w    = (const float*)d_in[7];
  const float* m_b    = (const float*)d_in[8];
  const float* z1_w   = (const float*)d_in[9];
  const float* z1_b   = (const float*)d_in[10];
  const float* z2_w   = (const float*)d_in[11];
  const float* z2_b   = (const float*)d_in[12];
  float* out = (float*)d_out;
  float* ws  = (float*)d_ws;

  float* ic     = ws;
  float* ih     = ws + 524288;
  float* im     = ws + 1048576;
  float* gates  = ws + 1572864;
  float* gnst   = ws + 3670016;
  float* qkv    = ws + 3670272;
  float* mkv    = ws + 5243136;
  float* stats  = ws + 6291712;
  float* cat2   = ws + 6357248;
  float* zc     = ws + 7405824;
  unsigned short* wpack = (unsigned short*)(ws + 8454400);
  float* g2     = gates;              // reuse after gnlstm

  // zero initial states ih, ic, im (contiguous)
  hipMemsetAsync(ic, 0, (size_t)3 * 524288 * sizeof(float), stream);
  // prepack conv weights to MFMA layout
  wprep_kernel<<<dim3(1440), 256, 0, stream>>>(conv_w, wpack);

  for (int t = 0; t < 8; ++t) {
    conv3_mfma_kernel<<<dim3(16, 8, 2), 256, 0, stream>>>(
        x, ih, wpack, conv_b, gates, t);
    gnstats_kernel<<<dim3(8, 8), 256, 0, stream>>>(gates, gnst);
    gnlstm_kernel<<<dim3(64, 8), 256, 0, stream>>>(gates, gnst, gn_g,
                                                   gn_b, ic, cat2, out);
    // projections: h_qkv = h_w @ oh (oh = cat2 rows 64..127); m_kv = m_w @ im
    gemm_kernel<<<dim3(16, 3, 8), 256, 0, stream>>>(
        h_w, cat2 + 65536, h_b, qkv, 64, 131072, 196608);
    gemm_kernel<<<dim3(16, 2, 8), 256, 0, stream>>>(
        m_w, im, m_b, mkv, 64, 65536, 131072);
    att_stats_kernel<<<dim3(16, 2, 8), 256, 0, stream>>>(qkv, mkv, stats);
    att_z_kernel<<<dim3(16, 2, 8), 256, 0, stream>>>(qkv, mkv, stats, zc);
    // z1: Zc = z1_w @ zc -> cat2 top half
    gemm_kernel<<<dim3(16, 1, 8), 256, 0, stream>>>(
        z1_w, zc, z1_b, cat2, 128, 131072, 131072);
    // z2: gates2 = z2_w @ cat2
    gemm_kernel<<<dim3(16, 3, 8), 256, 0, stream>>>(
        z2_w, cat2, z2_b, g2, 128, 131072, 196608);
    sam_kernel<<<dim3(64, 8), 256, 0, stream>>>(g2, im, ih, out, t);
  }
}